// Round 5
// baseline (276.196 us; speedup 1.0000x reference)
//
#include <hip/hip_runtime.h>

// Photonic layer: U = product of 2016 MZI 2x2 rotations (Reck mesh), then
// out = x @ U.T (complex), then tiny first-order Kerr phase rotation.
//
// R12. R11 post-mortem: build stuck at 99us, VGPR=148 -> compiler again
// refused the 32x float4 LDS batch and left a per-step dependent ds_read
// chain (2016 x ~120cyc = the whole 99us; VALUBusy ~0 = wave asleep on
// lgkmcnt). Structural fix: NO memory in the chain at all. Weights are
// distributed across lanes in registers (lane l holds the slot-l weight of
// every layer; wre/wim[63] static-indexed), and each step's wave-uniform
// scalar weight comes from v_readlane (compile-time lane index, ~2cyc,
// no memory). Chain = pure straight-line VALU: 2016 x (2 readlane + 8
// FMA/MUL) ~ 17us predicted.
// apply_mfma / tail_kernel / launcher: byte-identical to harness-verified
// R11 (clean A/B on build).

#define PSIZE 64
#define N_PHASES 2016
#define NLAYER 63
#define LOSS_AMP 0.99426007f
#define NL_COEFF 2.6e-17f

#define UF32_BYTES (2 * PSIZE * PSIZE * 4)    // 32 KB f32 complex U
#define WSPLIT_BYTES (4 * PSIZE * PSIZE * 2)  // 32 KB: Urh,Url,Uih,Uil bf16
#define WS_NEED (UF32_BYTES + WSPLIT_BYTES)

typedef __attribute__((ext_vector_type(8))) short sh8;    // 8 bf16 (4 VGPR)
typedef __attribute__((ext_vector_type(4))) float f32x4;  // MFMA C/D

__device__ __align__(16) float g_U_fallback[2 * PSIZE * PSIZE];

__device__ inline unsigned short f32_to_bf16_rn(float f) {
  unsigned int u = __float_as_uint(f);
  u += 0x7fffu + ((u >> 16) & 1u);   // round to nearest even
  return (unsigned short)(u >> 16);
}
__device__ inline float bf16_to_f32(unsigned short h) {
  return __uint_as_float(((unsigned int)h) << 16);
}

// Wave-uniform broadcast of lane `l` (compile-time) -> SGPR. Ignores exec;
// all 64 lanes are active wherever this is used.
__device__ inline float rdlane(float v, int l) {
  return __int_as_float(__builtin_amdgcn_readlane(__float_as_int(v), l));
}

// v_cvt_pk_bf16_f32: dst[15:0]=bf16(a), dst[31:16]=bf16(b). No builtin on
// gfx950 (guide T12) -> inline asm. Non-volatile pure dataflow.
__device__ inline unsigned pkbf16(float a, float b) {
  unsigned r;
  asm("v_cvt_pk_bf16_f32 %0, %1, %2" : "=v"(r) : "v"(a), "v"(b));
  return r;
}
__device__ inline float lo16f(unsigned u) { return __uint_as_float(u << 16); }
__device__ inline float hi16f(unsigned u) {
  return __uint_as_float(u & 0xFFFF0000u);
}
__device__ inline sh8 mk8(unsigned a, unsigned b, unsigned c, unsigned d) {
  union { unsigned u[4]; sh8 s; } t;
  t.u[0] = a; t.u[1] = b; t.u[2] = c; t.u[3] = d;
  return t.s;
}

// ---------------------------------------------------------------------------
// build: 1 block x 64 threads (1 wave), zero LDS.
// Precompute: lane l holds the slot-l weight of every layer li >= l in
// registers (wre/wim[63], static indices; garbage for li < l, never read).
// Chain: fully unrolled 2016 steps; per-step weight via readlane(., m).
// ---------------------------------------------------------------------------
__global__ __launch_bounds__(64, 1) void build_kernel(
    const float* __restrict__ phases,
    float* __restrict__ Uf32,            // null -> g_U_fallback
    unsigned short* __restrict__ Wout) { // null -> skip split output
  const int tid = threadIdx.x;           // == lane (1 wave)

  // Per-lane weight precompute. p = li(li+1)/2 + l, valid iff l <= li.
  float wre[NLAYER], wim[NLAYER];
#pragma unroll
  for (int li = 0; li < NLAYER; ++li) {
    float c = 1.0f, s = 0.0f;
    if (tid <= li) {                     // predicated; guards OOB load too
      const float th = phases[(li * (li + 1)) / 2 + tid];
      c = LOSS_AMP * cosf(th);
      s = LOSS_AMP * sinf(th);
    }
    wre[li] = c;
    wim[li] = s;
  }

  float ure[PSIZE], uim[PSIZE];
#pragma unroll
  for (int r = 0; r < PSIZE; ++r) {
    ure[r] = (r == tid) ? 1.0f : 0.0f;
    uim[r] = 0.0f;
  }

  // The MZI chain: straight-line VALU, no memory, no branches.
#pragma unroll
  for (int li = 0; li < NLAYER; ++li) {
#pragma unroll
    for (int m = 0; m <= li; ++m) {
      const float wc = rdlane(wre[li], m);
      const float ws = rdlane(wim[li], m);
      const float are = ure[m], aim = uim[m];
      const float bre = ure[m + 1], bim = uim[m + 1];
      ure[m]     = fmaf(wc, are, -ws * bim);
      uim[m]     = fmaf(wc, aim,  ws * bre);
      ure[m + 1] = fmaf(wc, bre, -ws * aim);
      uim[m + 1] = fmaf(wc, bim,  ws * are);
    }
  }

  // f32 U for tail/fallback: float2[r*64 + c] = U[r][c], c = tid.
  float* Udst = (Uf32 != nullptr) ? Uf32 : g_U_fallback;
#pragma unroll
  for (int r = 0; r < PSIZE; ++r)
    ((float2*)Udst)[r * PSIZE + tid] = make_float2(ure[r], uim[r]);

  // bf16 split B-matrices: W[mat][n][k] = {Urh,Url,Uih,Uil}[n][k], k = tid.
  // 16B k-slots XOR-swizzled by (n&7) so fragment ds_read_b128 is ~2-way.
  if (Wout != nullptr) {
    const int slot = tid >> 3, kin = tid & 7;
#pragma unroll
    for (int n = 0; n < PSIZE; ++n) {
      const int base = n * 64 + ((slot ^ (n & 7)) << 3) + kin;
      const unsigned short rh = f32_to_bf16_rn(ure[n]);
      const unsigned short rl = f32_to_bf16_rn(ure[n] - bf16_to_f32(rh));
      const unsigned short ih = f32_to_bf16_rn(uim[n]);
      const unsigned short il = f32_to_bf16_rn(uim[n] - bf16_to_f32(ih));
      Wout[0 * 4096 + base] = rh;
      Wout[1 * 4096 + base] = rl;
      Wout[2 * 4096 + base] = ih;
      Wout[3 * 4096 + base] = il;
    }
  }
}

// ---------------------------------------------------------------------------
// apply (MFMA): 256 threads = 4 waves; wave handles 32 rows (2 M-tiles of
// 16x16x32), full N=64 (4 N-tiles), K=64 (2 k-steps). Block = 128 rows.
// A/B share the logical-k mapping (permutation cancels); C/D: col = l&15,
// row = 4*(l>>4)+reg [guide, m89-verified; R10/R11 harness-verified].
// ---------------------------------------------------------------------------
__global__ __launch_bounds__(256, 2) void apply_mfma(
    const unsigned short* __restrict__ W,
    const float* __restrict__ xr,
    const float* __restrict__ xi,
    float* __restrict__ out_re,
    float* __restrict__ out_im) {  // null -> real-only
  __shared__ __align__(16) unsigned short sW[4 * PSIZE * PSIZE];  // 32 KB
  {
    const float4* src = (const float4*)W;
    float4* dst = (float4*)sW;
    for (int i = threadIdx.x; i < WSPLIT_BYTES / 16; i += 256) dst[i] = src[i];
  }
  __syncthreads();

  const int lane = threadIdx.x & 63;
  const int wave = threadIdx.x >> 6;
  const int lm = lane & 15;
  const int lg = lane >> 4;
  const long row0 = (long)blockIdx.x * 128 + (long)wave * 32;

  f32x4 accRe[2][4], accIm[2][4];
#pragma unroll
  for (int a = 0; a < 2; ++a)
#pragma unroll
    for (int b = 0; b < 4; ++b) {
      accRe[a][b] = f32x4{0.f, 0.f, 0.f, 0.f};
      accIm[a][b] = f32x4{0.f, 0.f, 0.f, 0.f};
    }

#pragma unroll
  for (int ks = 0; ks < 2; ++ks) {
    // A-fragments: bf16 hi/lo of xr, xi, -xi via v_cvt_pk_bf16_f32.
    sh8 arh[2], arl[2], aih[2], ail[2], anh[2], anl[2];
#pragma unroll
    for (int mt = 0; mt < 2; ++mt) {
      const long r = row0 + mt * 16 + lm;
      const float4* pr = (const float4*)(xr + r * PSIZE + ks * 32 + lg * 8);
      const float4* pi = (const float4*)(xi + r * PSIZE + ks * 32 + lg * 8);
      const float4 v0 = pr[0], v1 = pr[1];
      const float4 w0 = pi[0], w1 = pi[1];

      const unsigned rh0 = pkbf16(v0.x, v0.y), rh1 = pkbf16(v0.z, v0.w);
      const unsigned rh2 = pkbf16(v1.x, v1.y), rh3 = pkbf16(v1.z, v1.w);
      const unsigned rl0 = pkbf16(v0.x - lo16f(rh0), v0.y - hi16f(rh0));
      const unsigned rl1 = pkbf16(v0.z - lo16f(rh1), v0.w - hi16f(rh1));
      const unsigned rl2 = pkbf16(v1.x - lo16f(rh2), v1.y - hi16f(rh2));
      const unsigned rl3 = pkbf16(v1.z - lo16f(rh3), v1.w - hi16f(rh3));
      arh[mt] = mk8(rh0, rh1, rh2, rh3);
      arl[mt] = mk8(rl0, rl1, rl2, rl3);

      const unsigned ih0 = pkbf16(w0.x, w0.y), ih1 = pkbf16(w0.z, w0.w);
      const unsigned ih2 = pkbf16(w1.x, w1.y), ih3 = pkbf16(w1.z, w1.w);
      const unsigned il0 = pkbf16(w0.x - lo16f(ih0), w0.y - hi16f(ih0));
      const unsigned il1 = pkbf16(w0.z - lo16f(ih1), w0.w - hi16f(ih1));
      const unsigned il2 = pkbf16(w1.x - lo16f(ih2), w1.y - hi16f(ih2));
      const unsigned il3 = pkbf16(w1.z - lo16f(ih3), w1.w - hi16f(ih3));
      aih[mt] = mk8(ih0, ih1, ih2, ih3);
      ail[mt] = mk8(il0, il1, il2, il3);
      anh[mt] = mk8(ih0 ^ 0x80008000u, ih1 ^ 0x80008000u,
                    ih2 ^ 0x80008000u, ih3 ^ 0x80008000u);
      anl[mt] = mk8(il0 ^ 0x80008000u, il1 ^ 0x80008000u,
                    il2 ^ 0x80008000u, il3 ^ 0x80008000u);
    }

#pragma unroll
    for (int nt = 0; nt < 4; ++nt) {
      const int n = nt * 16 + lm;
      const int sidx = n * 64 + (((ks * 4 + lg) ^ (n & 7)) << 3);
      const sh8 bRh = *(const sh8*)&sW[0 * 4096 + sidx];
      const sh8 bRl = *(const sh8*)&sW[1 * 4096 + sidx];
      const sh8 bIh = *(const sh8*)&sW[2 * 4096 + sidx];
      const sh8 bIl = *(const sh8*)&sW[3 * 4096 + sidx];
#pragma unroll
      for (int mt = 0; mt < 2; ++mt) {
        f32x4 cr = accRe[mt][nt];
        cr = __builtin_amdgcn_mfma_f32_16x16x32_bf16(arh[mt], bRh, cr, 0, 0, 0);
        cr = __builtin_amdgcn_mfma_f32_16x16x32_bf16(arh[mt], bRl, cr, 0, 0, 0);
        cr = __builtin_amdgcn_mfma_f32_16x16x32_bf16(arl[mt], bRh, cr, 0, 0, 0);
        cr = __builtin_amdgcn_mfma_f32_16x16x32_bf16(anh[mt], bIh, cr, 0, 0, 0);
        cr = __builtin_amdgcn_mfma_f32_16x16x32_bf16(anh[mt], bIl, cr, 0, 0, 0);
        cr = __builtin_amdgcn_mfma_f32_16x16x32_bf16(anl[mt], bIh, cr, 0, 0, 0);
        accRe[mt][nt] = cr;
        f32x4 ci = accIm[mt][nt];
        ci = __builtin_amdgcn_mfma_f32_16x16x32_bf16(arh[mt], bIh, ci, 0, 0, 0);
        ci = __builtin_amdgcn_mfma_f32_16x16x32_bf16(arh[mt], bIl, ci, 0, 0, 0);
        ci = __builtin_amdgcn_mfma_f32_16x16x32_bf16(arl[mt], bIh, ci, 0, 0, 0);
        ci = __builtin_amdgcn_mfma_f32_16x16x32_bf16(aih[mt], bRh, ci, 0, 0, 0);
        ci = __builtin_amdgcn_mfma_f32_16x16x32_bf16(aih[mt], bRl, ci, 0, 0, 0);
        ci = __builtin_amdgcn_mfma_f32_16x16x32_bf16(ail[mt], bRh, ci, 0, 0, 0);
        accIm[mt][nt] = ci;
      }
    }
  }

  // Epilogue: Kerr rotation; 16-lane groups write 64B contiguous segments.
#pragma unroll
  for (int mt = 0; mt < 2; ++mt) {
#pragma unroll
    for (int reg = 0; reg < 4; ++reg) {
      const long row = row0 + mt * 16 + lg * 4 + reg;
#pragma unroll
      for (int nt = 0; nt < 4; ++nt) {
        const int col = nt * 16 + lm;
        const float re = accRe[mt][nt][reg];
        const float im = accIm[mt][nt][reg];
        const float p = NL_COEFF * fmaf(re, re, im * im);
        out_re[row * PSIZE + col] = fmaf(-im, p, re);
        if (out_im != nullptr) out_im[row * PSIZE + col] = fmaf(re, p, im);
      }
    }
  }
}

// ---------------------------------------------------------------------------
// tail / fallback: R9's harness-verified VALU apply, + rowStart offset.
// ---------------------------------------------------------------------------
__global__ __launch_bounds__(256, 2) void tail_kernel(
    const float* __restrict__ Usrc,   // null -> g_U_fallback
    const float* __restrict__ xr,
    const float* __restrict__ xi,
    float* __restrict__ out_re,
    float* __restrict__ out_im,
    long rowStart, long nrows) {
  __shared__ __align__(16) float sU[2 * PSIZE * PSIZE];  // 32 KB
  {
    const float4* g4 = (const float4*)((Usrc != nullptr) ? Usrc : g_U_fallback);
    float4* s4 = (float4*)sU;
    for (int i = threadIdx.x; i < (2 * PSIZE * PSIZE) / 4; i += 256)
      s4[i] = g4[i];
  }
  __syncthreads();

  const long row = rowStart + (long)blockIdx.x * 256 + threadIdx.x;
  if (row >= nrows) return;

  const float4* xr4 = (const float4*)(xr + (size_t)row * PSIZE);
  const float4* xi4 = (const float4*)(xi + (size_t)row * PSIZE);

  float aR[PSIZE], aI[PSIZE];
#pragma unroll
  for (int j = 0; j < PSIZE; ++j) { aR[j] = 0.0f; aI[j] = 0.0f; }

  const float4* su4 = (const float4*)sU;

#pragma unroll 1
  for (int kc = 0; kc < 8; ++kc) {
    const float4 a0 = xr4[2 * kc];
    const float4 a1 = xr4[2 * kc + 1];
    const float4 b0 = xi4[2 * kc];
    const float4 b1 = xi4[2 * kc + 1];
    const float4* up = su4 + kc * 4;
#pragma unroll
    for (int j = 0; j < PSIZE; ++j) {
      const float4 u0 = up[j * 32 + 0];
      const float4 u1 = up[j * 32 + 1];
      const float4 u2 = up[j * 32 + 2];
      const float4 u3 = up[j * 32 + 3];
      float r = aR[j], m = aI[j];
      r = fmaf(a0.x, u0.x, r); r = fmaf(-b0.x, u0.y, r);
      m = fmaf(a0.x, u0.y, m); m = fmaf( b0.x, u0.x, m);
      r = fmaf(a0.y, u0.z, r); r = fmaf(-b0.y, u0.w, r);
      m = fmaf(a0.y, u0.w, m); m = fmaf( b0.y, u0.z, m);
      r = fmaf(a0.z, u1.x, r); r = fmaf(-b0.z, u1.y, r);
      m = fmaf(a0.z, u1.y, m); m = fmaf( b0.z, u1.x, m);
      r = fmaf(a0.w, u1.z, r); r = fmaf(-b0.w, u1.w, r);
      m = fmaf(a0.w, u1.w, m); m = fmaf( b0.w, u1.z, m);
      r = fmaf(a1.x, u2.x, r); r = fmaf(-b1.x, u2.y, r);
      m = fmaf(a1.x, u2.y, m); m = fmaf( b1.x, u2.x, m);
      r = fmaf(a1.y, u2.z, r); r = fmaf(-b1.y, u2.w, r);
      m = fmaf(a1.y, u2.w, m); m = fmaf( b1.y, u2.z, m);
      r = fmaf(a1.z, u3.x, r); r = fmaf(-b1.z, u3.y, r);
      m = fmaf(a1.z, u3.y, m); m = fmaf( b1.z, u3.x, m);
      r = fmaf(a1.w, u3.z, r); r = fmaf(-b1.w, u3.w, r);
      m = fmaf(a1.w, u3.w, m); m = fmaf( b1.w, u3.z, m);
      aR[j] = r; aI[j] = m;
    }
  }

  float* orp = out_re + (size_t)row * PSIZE;
  float* oip = (out_im != nullptr) ? (out_im + (size_t)row * PSIZE) : nullptr;
#pragma unroll
  for (int jq = 0; jq < 16; ++jq) {
    const int j = 4 * jq;
    float4 vr, vi;
    {
      const float p = NL_COEFF * fmaf(aR[j], aR[j], aI[j] * aI[j]);
      vr.x = fmaf(-aI[j], p, aR[j]); vi.x = fmaf(aR[j], p, aI[j]);
    }
    {
      const float p = NL_COEFF * fmaf(aR[j+1], aR[j+1], aI[j+1] * aI[j+1]);
      vr.y = fmaf(-aI[j+1], p, aR[j+1]); vi.y = fmaf(aR[j+1], p, aI[j+1]);
    }
    {
      const float p = NL_COEFF * fmaf(aR[j+2], aR[j+2], aI[j+2] * aI[j+2]);
      vr.z = fmaf(-aI[j+2], p, aR[j+2]); vi.z = fmaf(aR[j+2], p, aI[j+2]);
    }
    {
      const float p = NL_COEFF * fmaf(aR[j+3], aR[j+3], aI[j+3] * aI[j+3]);
      vr.w = fmaf(-aI[j+3], p, aR[j+3]); vi.w = fmaf(aR[j+3], p, aI[j+3]);
    }
    ((float4*)orp)[jq] = vr;
    if (oip != nullptr) ((float4*)oip)[jq] = vi;
  }
}

extern "C" void kernel_launch(void* const* d_in, const int* in_sizes, int n_in,
                              void* d_out, int out_size, void* d_ws, size_t ws_size,
                              hipStream_t stream) {
  // Identify inputs by size, not position: phases has exactly 2016 elements.
  int pidx = -1;
  for (int i = 0; i < n_in; ++i) {
    if (in_sizes[i] == N_PHASES) { pidx = i; break; }
  }
  if (pidx < 0) pidx = 2;
  int xa = -1, xb = -1;
  for (int i = 0; i < n_in; ++i) {
    if (i == pidx) continue;
    if (xa < 0) xa = i;
    else if (xb < 0) xb = i;
  }
  if (xa < 0 || xb < 0) return;

  const float* phases = (const float*)d_in[pidx];
  const float* x_real = (const float*)d_in[xa];
  const float* x_imag = (const float*)d_in[xb];

  long b_in = (long)in_sizes[xa] / PSIZE;
  if ((long)in_sizes[xb] / PSIZE < b_in) b_in = (long)in_sizes[xb] / PSIZE;

  float* out = (float*)d_out;
  float* out_re = out;
  float* out_im = nullptr;
  long nrows;

  if ((long)out_size >= 2 * b_in * PSIZE) {
    const long half = (long)out_size / 2;     // planar [re | im]
    out_im = out + half;
    long cap = half / PSIZE;
    nrows = (b_in < cap) ? b_in : cap;
  } else {
    long cap = (long)out_size / PSIZE;        // real-part-only
    nrows = (b_in < cap) ? b_in : cap;
  }
  if (nrows <= 0) return;

  float* Uf32 = nullptr;
  unsigned short* Wsplit = nullptr;
  if (d_ws != nullptr && ws_size >= (size_t)WS_NEED) {
    Uf32 = (float*)d_ws;
    Wsplit = (unsigned short*)((char*)d_ws + UF32_BYTES);
  }

  build_kernel<<<1, 64, 0, stream>>>(phases, Uf32, Wsplit);

  const long ntiles = (Wsplit != nullptr) ? (nrows / 128) : 0;
  if (ntiles > 0) {
    apply_mfma<<<(int)ntiles, 256, 0, stream>>>(Wsplit, x_real, x_imag,
                                                out_re, out_im);
  }
  const long done = ntiles * 128;
  if (done < nrows) {
    const long rem = nrows - done;
    const int tblocks = (int)((rem + 255) / 256);
    tail_kernel<<<tblocks, 256, 0, stream>>>(Uf32, x_real, x_imag,
                                             out_re, out_im, done, nrows);
  }
}

// Round 6
// 231.699 us; speedup vs baseline: 1.1920x; 1.1920x over previous
//
#include <hip/hip_runtime.h>

// Photonic layer: U = product of 2016 MZI 2x2 rotations (Reck mesh), then
// out = x @ U.T (complex), then tiny first-order Kerr phase rotation.
//
// R13. R12 post-mortem: all single-wave builds (R10-R12) pinned at ~99us by
// a register-pressure cliff -- the full chain needs state(128) + weights
// (126-128) > 256 VGPR, so the allocator demoted arrays to scratch
// (R12: VGPR_Count=100, L2-latency-bound chain, VALUBusy ~0.03%).
// Fix: segment-parallel build. Waves 0-3 each evolve a 16-layer segment
// matrix S_w in registers (live set ~150 << 256); then U = S3*S2*S1*S0 via
// two LDS combine passes (P10=S1*S0 & P32=S3*S2 in parallel, then P32*P10),
// writing Uf32 + bf16-split W straight from registers.
// apply_mfma / tail_kernel / launcher: byte-identical to harness-verified
// R12 (clean A/B on build).

#define PSIZE 64
#define N_PHASES 2016
#define NLAYER 63
#define LOSS_AMP 0.99426007f
#define NL_COEFF 2.6e-17f

#define UF32_BYTES (2 * PSIZE * PSIZE * 4)    // 32 KB f32 complex U
#define WSPLIT_BYTES (4 * PSIZE * PSIZE * 2)  // 32 KB: Urh,Url,Uih,Uil bf16
#define WS_NEED (UF32_BYTES + WSPLIT_BYTES)

typedef __attribute__((ext_vector_type(8))) short sh8;    // 8 bf16 (4 VGPR)
typedef __attribute__((ext_vector_type(4))) float f32x4;  // MFMA C/D

__device__ __align__(16) float g_U_fallback[2 * PSIZE * PSIZE];

__device__ inline unsigned short f32_to_bf16_rn(float f) {
  unsigned int u = __float_as_uint(f);
  u += 0x7fffu + ((u >> 16) & 1u);   // round to nearest even
  return (unsigned short)(u >> 16);
}
__device__ inline float bf16_to_f32(unsigned short h) {
  return __uint_as_float(((unsigned int)h) << 16);
}

// Wave-uniform broadcast of lane `l` (compile-time) -> SGPR. Ignores exec.
__device__ inline float rdlane(float v, int l) {
  return __int_as_float(__builtin_amdgcn_readlane(__float_as_int(v), l));
}

// v_cvt_pk_bf16_f32: dst[15:0]=bf16(a), dst[31:16]=bf16(b). No builtin on
// gfx950 (guide T12) -> inline asm. Non-volatile pure dataflow.
__device__ inline unsigned pkbf16(float a, float b) {
  unsigned r;
  asm("v_cvt_pk_bf16_f32 %0, %1, %2" : "=v"(r) : "v"(a), "v"(b));
  return r;
}
__device__ inline float lo16f(unsigned u) { return __uint_as_float(u << 16); }
__device__ inline float hi16f(unsigned u) {
  return __uint_as_float(u & 0xFFFF0000u);
}
__device__ inline sh8 mk8(unsigned a, unsigned b, unsigned c, unsigned d) {
  union { unsigned u[4]; sh8 s; } t;
  t.u[0] = a; t.u[1] = b; t.u[2] = c; t.u[3] = d;
  return t.s;
}

// ---------------------------------------------------------------------------
// build: 1 block x 512 threads (8 waves). LDS = 128 KB:
//   sS[0..2]  : segment/product matrices (3 x 32 KB)
//   sWsm      : weight grid (64 layers x 64 slots), later reused for S_3.
// Phase A: all threads fill sWsm (layer 63 + pads = identity).
// Phase B: wave w<4 evolves columns of S_w = product of layers [16w,16w+16)
//          (state in regs, lane = column; per layer one ds_read_b64 then 63
//          unrolled identity-padded steps via readlane).
// Combine: pass1 P10=S1*S0 (waves 0-3) / P32=S3*S2 (waves 4-7) -> regs ->
//          sS[0]/sS[1]; pass2 U = P32*P10 (8 rows/thread) -> epilogue.
// ---------------------------------------------------------------------------
__global__ __launch_bounds__(512, 1) void build_kernel(
    const float* __restrict__ phases,
    float* __restrict__ Uf32,            // null -> g_U_fallback
    unsigned short* __restrict__ Wout) { // null -> skip split output
  __shared__ float2 sS[3][PSIZE * PSIZE];   // 96 KB
  __shared__ float2 sWsm[PSIZE * PSIZE];    // 32 KB (weights, then S_3)
  const int tid = threadIdx.x;
  const int wv = tid >> 6;                  // wave 0..7
  const int lane = tid & 63;

  // --- Phase A: weight grid (64 layers x 64 slots) ---
  for (int idx = tid; idx < PSIZE * PSIZE; idx += 512) {
    const int li = idx >> 6;          // layer 0..63 (63 = identity pad layer)
    const int m = idx & 63;           // slot 0..63
    float2 w = make_float2(1.0f, 0.0f);
    if (li < NLAYER && m <= li) {
      const float th = phases[(li * (li + 1)) / 2 + m];
      w = make_float2(LOSS_AMP * cosf(th), LOSS_AMP * sinf(th));
    }
    sWsm[idx] = w;
  }
  __syncthreads();

  // --- Phase B: segment chains (waves 0..3), state in registers ---
  float ure[PSIZE], uim[PSIZE];
  if (wv < 4) {
#pragma unroll
    for (int r = 0; r < PSIZE; ++r) {
      ure[r] = (r == lane) ? 1.0f : 0.0f;
      uim[r] = 0.0f;
    }
    for (int l = 0; l < 16; ++l) {          // rolled: code stays ~6 KB
      const int li = wv * 16 + l;           // seg 3 hits li=63 = identity
      const float2 w2 = sWsm[li * 64 + lane];  // lane m holds slot-m weight
#pragma unroll
      for (int m = 0; m < NLAYER; ++m) {    // pads: wc=1,ws=0 exact no-op
        const float wc = rdlane(w2.x, m);
        const float ws = rdlane(w2.y, m);
        const float are = ure[m], aim = uim[m];
        const float bre = ure[m + 1], bim = uim[m + 1];
        ure[m]     = fmaf(wc, are, -ws * bim);
        uim[m]     = fmaf(wc, aim,  ws * bre);
        ure[m + 1] = fmaf(wc, bre, -ws * aim);
        uim[m + 1] = fmaf(wc, bim,  ws * are);
      }
    }
  }
  __syncthreads();   // all chains done reading sWsm

  // --- Write segment matrices (S_3 reuses the weight region) ---
  if (wv < 4) {
    float2* dst = (wv == 3) ? sWsm : sS[wv];
#pragma unroll
    for (int r = 0; r < PSIZE; ++r)
      dst[r * 64 + lane] = make_float2(ure[r], uim[r]);
  }
  __syncthreads();

  // --- Pass 1: P10 = S1*S0 (waves 0-3), P32 = S3*S2 (waves 4-7) ---
  const int wg = wv >> 2;       // 0 or 1
  const int w4 = wv & 3;        // row block within product: rows 16*w4..+16
  {
    const float2* A  = (wg == 0) ? sS[1] : sWsm;   // S1 or S3 (left)
    const float2* Bm = (wg == 0) ? sS[0] : sS[2];  // S0 or S2 (right)
    float pre[16], pim[16];
#pragma unroll
    for (int r = 0; r < 16; ++r) { pre[r] = 0.f; pim[r] = 0.f; }
    for (int m = 0; m < PSIZE; ++m) {
      const float2 b = Bm[m * 64 + lane];          // per-lane, conflict-free
#pragma unroll
      for (int r = 0; r < 16; ++r) {
        const float2 a = A[(16 * w4 + r) * 64 + m]; // wave-uniform broadcast
        pre[r] = fmaf(a.x, b.x, fmaf(-a.y, b.y, pre[r]));
        pim[r] = fmaf(a.x, b.y, fmaf( a.y, b.x, pim[r]));
      }
    }
    __syncthreads();   // all pass-1 reads complete before overwrite
    float2* Pd = (wg == 0) ? sS[0] : sS[1];        // P10 -> sS[0], P32 -> sS[1]
#pragma unroll
    for (int r = 0; r < 16; ++r)
      Pd[(16 * w4 + r) * 64 + lane] = make_float2(pre[r], pim[r]);
  }
  __syncthreads();

  // --- Pass 2: U = P32 * P10; thread owns rows 8*wv..+8 of column `lane` ---
  float fre[8], fim[8];
#pragma unroll
  for (int r = 0; r < 8; ++r) { fre[r] = 0.f; fim[r] = 0.f; }
  for (int m = 0; m < PSIZE; ++m) {
    const float2 b = sS[0][m * 64 + lane];         // P10 column (per-lane)
#pragma unroll
    for (int r = 0; r < 8; ++r) {
      const float2 a = sS[1][(8 * wv + r) * 64 + m];  // P32 broadcast
      fre[r] = fmaf(a.x, b.x, fmaf(-a.y, b.y, fre[r]));
      fim[r] = fmaf(a.x, b.y, fmaf( a.y, b.x, fim[r]));
    }
  }

  // --- Epilogue: write Uf32 + bf16-split W straight from registers ---
  float* Udst = (Uf32 != nullptr) ? Uf32 : g_U_fallback;
#pragma unroll
  for (int r = 0; r < 8; ++r) {
    const int rr = 8 * wv + r;
    ((float2*)Udst)[rr * 64 + lane] = make_float2(fre[r], fim[r]);
  }
  if (Wout != nullptr) {
    const int slot = lane >> 3, kin = lane & 7;
#pragma unroll
    for (int r = 0; r < 8; ++r) {
      const int n = 8 * wv + r;                    // B-row (output col)
      const int base = n * 64 + ((slot ^ (n & 7)) << 3) + kin;
      const unsigned short rh = f32_to_bf16_rn(fre[r]);
      const unsigned short rl = f32_to_bf16_rn(fre[r] - bf16_to_f32(rh));
      const unsigned short ih = f32_to_bf16_rn(fim[r]);
      const unsigned short il = f32_to_bf16_rn(fim[r] - bf16_to_f32(ih));
      Wout[0 * 4096 + base] = rh;
      Wout[1 * 4096 + base] = rl;
      Wout[2 * 4096 + base] = ih;
      Wout[3 * 4096 + base] = il;
    }
  }
}

// ---------------------------------------------------------------------------
// apply (MFMA): byte-identical to harness-verified R12.
// ---------------------------------------------------------------------------
__global__ __launch_bounds__(256, 2) void apply_mfma(
    const unsigned short* __restrict__ W,
    const float* __restrict__ xr,
    const float* __restrict__ xi,
    float* __restrict__ out_re,
    float* __restrict__ out_im) {  // null -> real-only
  __shared__ __align__(16) unsigned short sW[4 * PSIZE * PSIZE];  // 32 KB
  {
    const float4* src = (const float4*)W;
    float4* dst = (float4*)sW;
    for (int i = threadIdx.x; i < WSPLIT_BYTES / 16; i += 256) dst[i] = src[i];
  }
  __syncthreads();

  const int lane = threadIdx.x & 63;
  const int wave = threadIdx.x >> 6;
  const int lm = lane & 15;
  const int lg = lane >> 4;
  const long row0 = (long)blockIdx.x * 128 + (long)wave * 32;

  f32x4 accRe[2][4], accIm[2][4];
#pragma unroll
  for (int a = 0; a < 2; ++a)
#pragma unroll
    for (int b = 0; b < 4; ++b) {
      accRe[a][b] = f32x4{0.f, 0.f, 0.f, 0.f};
      accIm[a][b] = f32x4{0.f, 0.f, 0.f, 0.f};
    }

#pragma unroll
  for (int ks = 0; ks < 2; ++ks) {
    // A-fragments: bf16 hi/lo of xr, xi, -xi via v_cvt_pk_bf16_f32.
    sh8 arh[2], arl[2], aih[2], ail[2], anh[2], anl[2];
#pragma unroll
    for (int mt = 0; mt < 2; ++mt) {
      const long r = row0 + mt * 16 + lm;
      const float4* pr = (const float4*)(xr + r * PSIZE + ks * 32 + lg * 8);
      const float4* pi = (const float4*)(xi + r * PSIZE + ks * 32 + lg * 8);
      const float4 v0 = pr[0], v1 = pr[1];
      const float4 w0 = pi[0], w1 = pi[1];

      const unsigned rh0 = pkbf16(v0.x, v0.y), rh1 = pkbf16(v0.z, v0.w);
      const unsigned rh2 = pkbf16(v1.x, v1.y), rh3 = pkbf16(v1.z, v1.w);
      const unsigned rl0 = pkbf16(v0.x - lo16f(rh0), v0.y - hi16f(rh0));
      const unsigned rl1 = pkbf16(v0.z - lo16f(rh1), v0.w - hi16f(rh1));
      const unsigned rl2 = pkbf16(v1.x - lo16f(rh2), v1.y - hi16f(rh2));
      const unsigned rl3 = pkbf16(v1.z - lo16f(rh3), v1.w - hi16f(rh3));
      arh[mt] = mk8(rh0, rh1, rh2, rh3);
      arl[mt] = mk8(rl0, rl1, rl2, rl3);

      const unsigned ih0 = pkbf16(w0.x, w0.y), ih1 = pkbf16(w0.z, w0.w);
      const unsigned ih2 = pkbf16(w1.x, w1.y), ih3 = pkbf16(w1.z, w1.w);
      const unsigned il0 = pkbf16(w0.x - lo16f(ih0), w0.y - hi16f(ih0));
      const unsigned il1 = pkbf16(w0.z - lo16f(ih1), w0.w - hi16f(ih1));
      const unsigned il2 = pkbf16(w1.x - lo16f(ih2), w1.y - hi16f(ih2));
      const unsigned il3 = pkbf16(w1.z - lo16f(ih3), w1.w - hi16f(ih3));
      aih[mt] = mk8(ih0, ih1, ih2, ih3);
      ail[mt] = mk8(il0, il1, il2, il3);
      anh[mt] = mk8(ih0 ^ 0x80008000u, ih1 ^ 0x80008000u,
                    ih2 ^ 0x80008000u, ih3 ^ 0x80008000u);
      anl[mt] = mk8(il0 ^ 0x80008000u, il1 ^ 0x80008000u,
                    il2 ^ 0x80008000u, il3 ^ 0x80008000u);
    }

#pragma unroll
    for (int nt = 0; nt < 4; ++nt) {
      const int n = nt * 16 + lm;
      const int sidx = n * 64 + (((ks * 4 + lg) ^ (n & 7)) << 3);
      const sh8 bRh = *(const sh8*)&sW[0 * 4096 + sidx];
      const sh8 bRl = *(const sh8*)&sW[1 * 4096 + sidx];
      const sh8 bIh = *(const sh8*)&sW[2 * 4096 + sidx];
      const sh8 bIl = *(const sh8*)&sW[3 * 4096 + sidx];
#pragma unroll
      for (int mt = 0; mt < 2; ++mt) {
        f32x4 cr = accRe[mt][nt];
        cr = __builtin_amdgcn_mfma_f32_16x16x32_bf16(arh[mt], bRh, cr, 0, 0, 0);
        cr = __builtin_amdgcn_mfma_f32_16x16x32_bf16(arh[mt], bRl, cr, 0, 0, 0);
        cr = __builtin_amdgcn_mfma_f32_16x16x32_bf16(arl[mt], bRh, cr, 0, 0, 0);
        cr = __builtin_amdgcn_mfma_f32_16x16x32_bf16(anh[mt], bIh, cr, 0, 0, 0);
        cr = __builtin_amdgcn_mfma_f32_16x16x32_bf16(anh[mt], bIl, cr, 0, 0, 0);
        cr = __builtin_amdgcn_mfma_f32_16x16x32_bf16(anl[mt], bIh, cr, 0, 0, 0);
        accRe[mt][nt] = cr;
        f32x4 ci = accIm[mt][nt];
        ci = __builtin_amdgcn_mfma_f32_16x16x32_bf16(arh[mt], bIh, ci, 0, 0, 0);
        ci = __builtin_amdgcn_mfma_f32_16x16x32_bf16(arh[mt], bIl, ci, 0, 0, 0);
        ci = __builtin_amdgcn_mfma_f32_16x16x32_bf16(arl[mt], bIh, ci, 0, 0, 0);
        ci = __builtin_amdgcn_mfma_f32_16x16x32_bf16(aih[mt], bRh, ci, 0, 0, 0);
        ci = __builtin_amdgcn_mfma_f32_16x16x32_bf16(aih[mt], bRl, ci, 0, 0, 0);
        ci = __builtin_amdgcn_mfma_f32_16x16x32_bf16(ail[mt], bRh, ci, 0, 0, 0);
        accIm[mt][nt] = ci;
      }
    }
  }

  // Epilogue: Kerr rotation; 16-lane groups write 64B contiguous segments.
#pragma unroll
  for (int mt = 0; mt < 2; ++mt) {
#pragma unroll
    for (int reg = 0; reg < 4; ++reg) {
      const long row = row0 + mt * 16 + lg * 4 + reg;
#pragma unroll
      for (int nt = 0; nt < 4; ++nt) {
        const int col = nt * 16 + lm;
        const float re = accRe[mt][nt][reg];
        const float im = accIm[mt][nt][reg];
        const float p = NL_COEFF * fmaf(re, re, im * im);
        out_re[row * PSIZE + col] = fmaf(-im, p, re);
        if (out_im != nullptr) out_im[row * PSIZE + col] = fmaf(re, p, im);
      }
    }
  }
}

// ---------------------------------------------------------------------------
// tail / fallback: R9's harness-verified VALU apply, + rowStart offset.
// ---------------------------------------------------------------------------
__global__ __launch_bounds__(256, 2) void tail_kernel(
    const float* __restrict__ Usrc,   // null -> g_U_fallback
    const float* __restrict__ xr,
    const float* __restrict__ xi,
    float* __restrict__ out_re,
    float* __restrict__ out_im,
    long rowStart, long nrows) {
  __shared__ __align__(16) float sU[2 * PSIZE * PSIZE];  // 32 KB
  {
    const float4* g4 = (const float4*)((Usrc != nullptr) ? Usrc : g_U_fallback);
    float4* s4 = (float4*)sU;
    for (int i = threadIdx.x; i < (2 * PSIZE * PSIZE) / 4; i += 256)
      s4[i] = g4[i];
  }
  __syncthreads();

  const long row = rowStart + (long)blockIdx.x * 256 + threadIdx.x;
  if (row >= nrows) return;

  const float4* xr4 = (const float4*)(xr + (size_t)row * PSIZE);
  const float4* xi4 = (const float4*)(xi + (size_t)row * PSIZE);

  float aR[PSIZE], aI[PSIZE];
#pragma unroll
  for (int j = 0; j < PSIZE; ++j) { aR[j] = 0.0f; aI[j] = 0.0f; }

  const float4* su4 = (const float4*)sU;

#pragma unroll 1
  for (int kc = 0; kc < 8; ++kc) {
    const float4 a0 = xr4[2 * kc];
    const float4 a1 = xr4[2 * kc + 1];
    const float4 b0 = xi4[2 * kc];
    const float4 b1 = xi4[2 * kc + 1];
    const float4* up = su4 + kc * 4;
#pragma unroll
    for (int j = 0; j < PSIZE; ++j) {
      const float4 u0 = up[j * 32 + 0];
      const float4 u1 = up[j * 32 + 1];
      const float4 u2 = up[j * 32 + 2];
      const float4 u3 = up[j * 32 + 3];
      float r = aR[j], m = aI[j];
      r = fmaf(a0.x, u0.x, r); r = fmaf(-b0.x, u0.y, r);
      m = fmaf(a0.x, u0.y, m); m = fmaf( b0.x, u0.x, m);
      r = fmaf(a0.y, u0.z, r); r = fmaf(-b0.y, u0.w, r);
      m = fmaf(a0.y, u0.w, m); m = fmaf( b0.y, u0.z, m);
      r = fmaf(a0.z, u1.x, r); r = fmaf(-b0.z, u1.y, r);
      m = fmaf(a0.z, u1.y, m); m = fmaf( b0.z, u1.x, m);
      r = fmaf(a0.w, u1.z, r); r = fmaf(-b0.w, u1.w, r);
      m = fmaf(a0.w, u1.w, m); m = fmaf( b0.w, u1.z, m);
      r = fmaf(a1.x, u2.x, r); r = fmaf(-b1.x, u2.y, r);
      m = fmaf(a1.x, u2.y, m); m = fmaf( b1.x, u2.x, m);
      r = fmaf(a1.y, u2.z, r); r = fmaf(-b1.y, u2.w, r);
      m = fmaf(a1.y, u2.w, m); m = fmaf( b1.y, u2.z, m);
      r = fmaf(a1.z, u3.x, r); r = fmaf(-b1.z, u3.y, r);
      m = fmaf(a1.z, u3.y, m); m = fmaf( b1.z, u3.x, m);
      r = fmaf(a1.w, u3.z, r); r = fmaf(-b1.w, u3.w, r);
      m = fmaf(a1.w, u3.w, m); m = fmaf( b1.w, u3.z, m);
      aR[j] = r; aI[j] = m;
    }
  }

  float* orp = out_re + (size_t)row * PSIZE;
  float* oip = (out_im != nullptr) ? (out_im + (size_t)row * PSIZE) : nullptr;
#pragma unroll
  for (int jq = 0; jq < 16; ++jq) {
    const int j = 4 * jq;
    float4 vr, vi;
    {
      const float p = NL_COEFF * fmaf(aR[j], aR[j], aI[j] * aI[j]);
      vr.x = fmaf(-aI[j], p, aR[j]); vi.x = fmaf(aR[j], p, aI[j]);
    }
    {
      const float p = NL_COEFF * fmaf(aR[j+1], aR[j+1], aI[j+1] * aI[j+1]);
      vr.y = fmaf(-aI[j+1], p, aR[j+1]); vi.y = fmaf(aR[j+1], p, aI[j+1]);
    }
    {
      const float p = NL_COEFF * fmaf(aR[j+2], aR[j+2], aI[j+2] * aI[j+2]);
      vr.z = fmaf(-aI[j+2], p, aR[j+2]); vi.z = fmaf(aR[j+2], p, aI[j+2]);
    }
    {
      const float p = NL_COEFF * fmaf(aR[j+3], aR[j+3], aI[j+3] * aI[j+3]);
      vr.w = fmaf(-aI[j+3], p, aR[j+3]); vi.w = fmaf(aR[j+3], p, aI[j+3]);
    }
    ((float4*)orp)[jq] = vr;
    if (oip != nullptr) ((float4*)oip)[jq] = vi;
  }
}

extern "C" void kernel_launch(void* const* d_in, const int* in_sizes, int n_in,
                              void* d_out, int out_size, void* d_ws, size_t ws_size,
                              hipStream_t stream) {
  // Identify inputs by size, not position: phases has exactly 2016 elements.
  int pidx = -1;
  for (int i = 0; i < n_in; ++i) {
    if (in_sizes[i] == N_PHASES) { pidx = i; break; }
  }
  if (pidx < 0) pidx = 2;
  int xa = -1, xb = -1;
  for (int i = 0; i < n_in; ++i) {
    if (i == pidx) continue;
    if (xa < 0) xa = i;
    else if (xb < 0) xb = i;
  }
  if (xa < 0 || xb < 0) return;

  const float* phases = (const float*)d_in[pidx];
  const float* x_real = (const float*)d_in[xa];
  const float* x_imag = (const float*)d_in[xb];

  long b_in = (long)in_sizes[xa] / PSIZE;
  if ((long)in_sizes[xb] / PSIZE < b_in) b_in = (long)in_sizes[xb] / PSIZE;

  float* out = (float*)d_out;
  float* out_re = out;
  float* out_im = nullptr;
  long nrows;

  if ((long)out_size >= 2 * b_in * PSIZE) {
    const long half = (long)out_size / 2;     // planar [re | im]
    out_im = out + half;
    long cap = half / PSIZE;
    nrows = (b_in < cap) ? b_in : cap;
  } else {
    long cap = (long)out_size / PSIZE;        // real-part-only
    nrows = (b_in < cap) ? b_in : cap;
  }
  if (nrows <= 0) return;

  float* Uf32 = nullptr;
  unsigned short* Wsplit = nullptr;
  if (d_ws != nullptr && ws_size >= (size_t)WS_NEED) {
    Uf32 = (float*)d_ws;
    Wsplit = (unsigned short*)((char*)d_ws + UF32_BYTES);
  }

  build_kernel<<<1, 512, 0, stream>>>(phases, Uf32, Wsplit);

  const long ntiles = (Wsplit != nullptr) ? (nrows / 128) : 0;
  if (ntiles > 0) {
    apply_mfma<<<(int)ntiles, 256, 0, stream>>>(Wsplit, x_real, x_imag,
                                                out_re, out_im);
  }
  const long done = ntiles * 128;
  if (done < nrows) {
    const long rem = nrows - done;
    const int tblocks = (int)((rem + 255) / 256);
    tail_kernel<<<tblocks, 256, 0, stream>>>(Uf32, x_real, x_imag,
                                             out_re, out_im, done, nrows);
  }
}